// Round 6
// baseline (459.974 us; speedup 1.0000x reference)
//
#include <hip/hip_runtime.h>

#define SEQ 2048
#define DIM 64

typedef __bf16 bf16x8 __attribute__((ext_vector_type(8)));
typedef float f32x4 __attribute__((ext_vector_type(4)));
typedef unsigned short u16x8 __attribute__((ext_vector_type(8)));
typedef unsigned short u16x4 __attribute__((ext_vector_type(4)));

__device__ __forceinline__ unsigned short f2bf(float f) {
    return __builtin_bit_cast(unsigned short, static_cast<__bf16>(f));
}

// 1024 blocks (16 q-tiles x 64 bh), 4 waves/block, 128 q-rows/block.
// Double-buffered K/V LDS. Prefetch of tile t+1 is issued with inline-asm
// global loads (compiler cannot sink them) BEFORE compute of tile t;
// vmcnt(0)+sched_barrier+ds_write after compute. One barrier per iteration.
__global__ __launch_bounds__(256, 4) void attn_fwd(
    const float* __restrict__ Qg, const float* __restrict__ Kg,
    const float* __restrict__ Vg, const int* __restrict__ Mg,
    float* __restrict__ Og)
{
    __shared__ unsigned short Ksh[2][64 * 64];   // K tile, row-major, XOR-swizzled
    __shared__ unsigned short Vsh[2][64 * 64];   // V^T tile [d][k], XOR-swizzled
    __shared__ unsigned short Psh[4][16 * 64];   // per-wave P half-tile, reused per qb

    const int tid = threadIdx.x;
    const int w = tid >> 6, lane = tid & 63;
    const int g = lane >> 4, c = lane & 15;
    const int bh = blockIdx.y, b = bh >> 4;      // H = 16
    const int hoff = bh * (SEQ * DIM);
    const int q0 = blockIdx.x * 128;
    const int qw0 = q0 + w * 32;

    // ---- Q fragments (B-operand layout): lane holds Q[qw0+16qb+c][32h+8g+i]
    const float QS = 0.18033688011112042f;       // (1/sqrt(64)) * log2(e)
    u16x8 qf[2][2];
    #pragma unroll
    for (int qb = 0; qb < 2; ++qb)
    #pragma unroll
    for (int h = 0; h < 2; ++h) {
        const float* qp = Qg + hoff + (qw0 + 16 * qb + c) * DIM + 32 * h + 8 * g;
        float4 x0 = *(const float4*)qp;
        float4 x1 = *(const float4*)(qp + 4);
        u16x8 u;
        u[0]=f2bf(x0.x*QS); u[1]=f2bf(x0.y*QS); u[2]=f2bf(x0.z*QS); u[3]=f2bf(x0.w*QS);
        u[4]=f2bf(x1.x*QS); u[5]=f2bf(x1.y*QS); u[6]=f2bf(x1.z*QS); u[7]=f2bf(x1.w*QS);
        qf[qb][h] = u;
    }

    f32x4 of[2][4];
    #pragma unroll
    for (int qb = 0; qb < 2; ++qb)
      #pragma unroll
      for (int n = 0; n < 4; ++n) of[qb][n] = (f32x4){0.f, 0.f, 0.f, 0.f};
    float m_run[2] = {-3e38f, -3e38f};
    float l_run[2] = {0.f, 0.f};

    unsigned short* const pw = Psh[w];

    // ---- staging state (register prefetch, forced by asm volatile)
    const int krow = tid >> 2, kseg = (tid & 3) << 4;    // K: [row][16-f32 segment]
    const int vd = tid & 63,  vkq = (tid >> 6) << 4;     // V^T: column gather
    float4 kpre0, kpre1, kpre2, kpre3;
    float  vpre[16];
    int mpre, mcur = 1;

    auto issueKV = [&](int kt0) {
        const float* kp = Kg + hoff + (kt0 + krow) * DIM + kseg;
        asm volatile("global_load_dwordx4 %0, %1, off"           : "=v"(kpre0) : "v"(kp));
        asm volatile("global_load_dwordx4 %0, %1, off offset:16" : "=v"(kpre1) : "v"(kp));
        asm volatile("global_load_dwordx4 %0, %1, off offset:32" : "=v"(kpre2) : "v"(kp));
        asm volatile("global_load_dwordx4 %0, %1, off offset:48" : "=v"(kpre3) : "v"(kp));
        const float* vp = Vg + hoff + (kt0 + vkq) * DIM + vd;
        #pragma unroll
        for (int i = 0; i < 8; ++i) {
            asm volatile("global_load_dword %0, %1, off offset:%2"
                         : "=v"(vpre[2 * i]) : "v"(vp), "i"(512 * i));
            asm volatile("global_load_dword %0, %1, off offset:%2"
                         : "=v"(vpre[2 * i + 1]) : "v"(vp), "i"(512 * i + 256));
        }
        const int* mp = Mg + b * SEQ + kt0 + lane;
        asm volatile("global_load_dword %0, %1, off" : "=v"(mpre) : "v"(mp));
    };
    auto waitKV = [&]() {
        asm volatile("s_waitcnt vmcnt(0)" ::: "memory");
        __builtin_amdgcn_sched_barrier(0);
    };
    auto writeKV = [&](int nbuf) {
        u16x8 u0, u1;
        u0[0]=f2bf(kpre0.x); u0[1]=f2bf(kpre0.y); u0[2]=f2bf(kpre0.z); u0[3]=f2bf(kpre0.w);
        u0[4]=f2bf(kpre1.x); u0[5]=f2bf(kpre1.y); u0[6]=f2bf(kpre1.z); u0[7]=f2bf(kpre1.w);
        u1[0]=f2bf(kpre2.x); u1[1]=f2bf(kpre2.y); u1[2]=f2bf(kpre2.z); u1[3]=f2bf(kpre2.w);
        u1[4]=f2bf(kpre3.x); u1[5]=f2bf(kpre3.y); u1[6]=f2bf(kpre3.z); u1[7]=f2bf(kpre3.w);
        const int sw = (krow & 7) << 3;
        *(u16x8*)&Ksh[nbuf][(krow * 64 + kseg) ^ sw] = u0;
        *(u16x8*)&Ksh[nbuf][(krow * 64 + kseg + 8) ^ sw] = u1;
        u16x8 v0, v1;
        #pragma unroll
        for (int i = 0; i < 8; ++i) { v0[i] = f2bf(vpre[i]); v1[i] = f2bf(vpre[i + 8]); }
        const int sw2 = (vd & 7) << 3;
        *(u16x8*)&Vsh[nbuf][(vd * 64 + vkq) ^ sw2] = v0;
        *(u16x8*)&Vsh[nbuf][(vd * 64 + vkq + 8) ^ sw2] = v1;
    };

    // ---- prologue: stage tile 0 into buffer 0
    issueKV(0);
    waitKV();
    writeKV(0);
    mcur = mpre;

    const int nt = 2 * blockIdx.x + 2;
    for (int t = 0; t < nt; ++t) {
        const int kt0 = t * 64;
        const int cur = t & 1;
        __syncthreads();                          // LDS[cur] ready for all waves
        const bool pf = (t + 1 < nt);
        if (pf) issueKV(kt0 + 64);                // asm: issues NOW, hides under compute

        if (kt0 < qw0 + 32) {                     // causal: this wave needs this tile
            unsigned long long bal = __ballot(mcur != 0);

            // K A-frags: lane holds K[16m+c][32h+8g+i]
            u16x8 ka[4][2];
            #pragma unroll
            for (int m = 0; m < 4; ++m)
              #pragma unroll
              for (int h = 0; h < 2; ++h)
                ka[m][h] = *(const u16x8*)&Ksh[cur][((m * 16 + c) * 64 + 32 * h + 8 * g) ^ ((c & 7) << 3)];

            // S^T[k][q]: C/D row = k (4g+r within 16-block m), col = q (c)
            f32x4 sv[4][2];
            __builtin_amdgcn_s_setprio(1);
            #pragma unroll
            for (int m = 0; m < 4; ++m)
              #pragma unroll
              for (int qb = 0; qb < 2; ++qb) {
                f32x4 acc = (f32x4){0.f, 0.f, 0.f, 0.f};
                acc = __builtin_amdgcn_mfma_f32_16x16x32_bf16(
                        __builtin_bit_cast(bf16x8, ka[m][0]),
                        __builtin_bit_cast(bf16x8, qf[qb][0]), acc, 0, 0, 0);
                acc = __builtin_amdgcn_mfma_f32_16x16x32_bf16(
                        __builtin_bit_cast(bf16x8, ka[m][1]),
                        __builtin_bit_cast(bf16x8, qf[qb][1]), acc, 0, 0, 0);
                sv[m][qb] = acc;
              }
            __builtin_amdgcn_s_setprio(0);

            // causal mask on the diagonal tile for this wave
            if (kt0 + 63 > qw0) {
                #pragma unroll
                for (int m = 0; m < 4; ++m)
                #pragma unroll
                for (int qb = 0; qb < 2; ++qb) {
                    const int base = kt0 + 16 * m + 4 * g - qw0 - 16 * qb;
                    #pragma unroll
                    for (int r = 0; r < 4; ++r)
                        if (base + r > c) sv[m][qb][r] = -3e38f;
                }
            }
            // padding mask (never taken for all-ones mask)
            if (bal != ~0ULL) {
                #pragma unroll
                for (int m = 0; m < 4; ++m)
                #pragma unroll
                for (int r = 0; r < 4; ++r)
                    if (!((bal >> (16 * m + 4 * g + r)) & 1ULL)) {
                        sv[m][0][r] = -3e38f; sv[m][1][r] = -3e38f;
                    }
            }

            // ---- online softmax per q = 16qb + c (base-2 domain)
            float alpha[2];
            #pragma unroll
            for (int qb = 0; qb < 2; ++qb) {
                float tm = -3e38f;
                #pragma unroll
                for (int m = 0; m < 4; ++m)
                  #pragma unroll
                  for (int r = 0; r < 4; ++r) tm = fmaxf(tm, sv[m][qb][r]);
                tm = fmaxf(tm, __shfl_xor(tm, 16));
                tm = fmaxf(tm, __shfl_xor(tm, 32));
                float mn = fmaxf(m_run[qb], tm);
                alpha[qb] = exp2f(m_run[qb] - mn);
                m_run[qb] = mn;
                float rs = 0.f;
                #pragma unroll
                for (int m = 0; m < 4; ++m)
                  #pragma unroll
                  for (int r = 0; r < 4; ++r) {
                      float p = exp2f(sv[m][qb][r] - mn);
                      sv[m][qb][r] = p;
                      rs += p;
                  }
                rs += __shfl_xor(rs, 16);
                rs += __shfl_xor(rs, 32);
                l_run[qb] = l_run[qb] * alpha[qb] + rs;
            }

            // rescale O accumulators by row-alpha (O rows are 16qb+4g+r)
            #pragma unroll
            for (int qb = 0; qb < 2; ++qb) {
                #pragma unroll
                for (int r = 0; r < 4; ++r) {
                    float ar = __shfl(alpha[qb], 4 * g + r);
                    #pragma unroll
                    for (int n = 0; n < 4; ++n) of[qb][n][r] *= ar;
                }
            }

            // ---- P half-tile -> per-wave LDS (bf16) then read as A-frags
            u16x8 ap[2][2];
            #pragma unroll
            for (int qb = 0; qb < 2; ++qb) {
                #pragma unroll
                for (int m = 0; m < 4; ++m) {
                    u16x4 pk;
                    #pragma unroll
                    for (int r = 0; r < 4; ++r) pk[r] = f2bf(sv[m][qb][r]);
                    *(u16x4*)&pw[(c * 64 + 16 * m + 4 * g) ^ ((c & 7) << 3)] = pk;
                }
                #pragma unroll
                for (int h = 0; h < 2; ++h)
                    ap[qb][h] = *(const u16x8*)&pw[(c * 64 + 32 * h + 8 * g) ^ ((c & 7) << 3)];
            }

            // ---- PV: O[q][d] += P[q][k] V[k][d]
            u16x8 vf[4][2];
            #pragma unroll
            for (int n = 0; n < 4; ++n)
              #pragma unroll
              for (int h = 0; h < 2; ++h)
                vf[n][h] = *(const u16x8*)&Vsh[cur][((16 * n + c) * 64 + 32 * h + 8 * g) ^ ((c & 7) << 3)];
            __builtin_amdgcn_s_setprio(1);
            #pragma unroll
            for (int qb = 0; qb < 2; ++qb)
              #pragma unroll
              for (int n = 0; n < 4; ++n) {
                of[qb][n] = __builtin_amdgcn_mfma_f32_16x16x32_bf16(
                    __builtin_bit_cast(bf16x8, ap[qb][0]),
                    __builtin_bit_cast(bf16x8, vf[n][0]), of[qb][n], 0, 0, 0);
                of[qb][n] = __builtin_amdgcn_mfma_f32_16x16x32_bf16(
                    __builtin_bit_cast(bf16x8, ap[qb][1]),
                    __builtin_bit_cast(bf16x8, vf[n][1]), of[qb][n], 0, 0, 0);
              }
            __builtin_amdgcn_s_setprio(0);
        }

        if (pf) {                                  // drain prefetch, write tile t+1
            waitKV();
            writeKV(cur ^ 1);
            mcur = mpre;
        }
    }

    // ---- epilogue: normalize by l and store (f32)
    #pragma unroll
    for (int qb = 0; qb < 2; ++qb) {
        #pragma unroll
        for (int r = 0; r < 4; ++r) {
            float lr = __shfl(l_run[qb], 4 * g + r);
            float inv = 1.0f / lr;
            #pragma unroll
            for (int n = 0; n < 4; ++n)
                Og[hoff + (qw0 + 16 * qb + 4 * g + r) * DIM + 16 * n + c] = of[qb][n][r] * inv;
        }
    }
}

extern "C" void kernel_launch(void* const* d_in, const int* in_sizes, int n_in,
                              void* d_out, int out_size, void* d_ws, size_t ws_size,
                              hipStream_t stream) {
    const float* Q = (const float*)d_in[0];
    const float* K = (const float*)d_in[1];
    const float* V = (const float*)d_in[2];
    const int*   M = (const int*)d_in[3];
    float*       O = (float*)d_out;
    dim3 grid(16, 64);
    attn_fwd<<<grid, 256, 0, stream>>>(Q, K, V, M, O);
}

// Round 7
// 236.732 us; speedup vs baseline: 1.9430x; 1.9430x over previous
//
#include <hip/hip_runtime.h>

#define SEQ 2048
#define DIM 64

typedef __bf16 bf16x8 __attribute__((ext_vector_type(8)));
typedef float f32x4 __attribute__((ext_vector_type(4)));
typedef unsigned short u16x8 __attribute__((ext_vector_type(8)));
typedef unsigned short u16x4 __attribute__((ext_vector_type(4)));

__device__ __forceinline__ unsigned short f2bf(float f) {
    return __builtin_bit_cast(unsigned short, static_cast<__bf16>(f));
}

// 1024 blocks: grid(64 bh, 16 y). qtile = 4*(y>>2) + ((y>>2)&1 ? 3-(y&3) : (y&3))
// -> under round-robin CU striding each CU's 4 blocks get qtiles
// {y0, 7-y0, 8+y0, 15-y0}: constant 68 tile-iters/CU (balance) with mixed
// phases (stall decorrelation). Same-bh blocks stride 64 -> same XCD L2.
// 4 waves/block; wave w owns q rows [q0+32w, q0+32w+32). KV tiles of 64.
// Swapped-QK orientation: S^T = mfma(A=K_tile, B=Q^T) so lane's q = lane&15.
__global__ __launch_bounds__(256) void attn_fwd(
    const float* __restrict__ Qg, const float* __restrict__ Kg,
    const float* __restrict__ Vg, const int* __restrict__ Mg,
    float* __restrict__ Og)
{
    __shared__ unsigned short Ksh[64 * 64];      // K tile, row-major, XOR-swizzled
    __shared__ unsigned short Vsh[64 * 64];      // V^T tile [d][k], XOR-swizzled
    __shared__ unsigned short Psh[4][32 * 64];   // per-wave P [q][k], XOR-swizzled
    __shared__ int mflags[4];

    const int tid = threadIdx.x;
    const int w = tid >> 6, lane = tid & 63;
    const int g = lane >> 4, c = lane & 15;
    const int bh = blockIdx.x, b = bh >> 4;      // H = 16
    const int yj = blockIdx.y >> 2, yi = blockIdx.y & 3;
    const int qt = 4 * yj + ((yj & 1) ? (3 - yi) : yi);
    const int q0 = qt * 128;
    const int qw0 = q0 + w * 32;
    const int hoff = bh * (SEQ * DIM);

    // ---- block-wide padding-mask check (mask is usually all-ones)
    {
        const int4* m4 = (const int4*)(Mg + b * SEQ) + tid * 2;
        int4 a = m4[0], bb = m4[1];
        bool ok = a.x && a.y && a.z && a.w && bb.x && bb.y && bb.z && bb.w;
        unsigned long long bal0 = __ballot(ok);
        if (lane == 0) mflags[w] = (bal0 == ~0ULL) ? 1 : 0;
    }

    // ---- Q fragments (B-operand layout): lane holds Q[qw0+16qb+c][32h+8g+i],
    //      scaled by (1/sqrt(D))*log2(e) so softmax runs in base-2 domain.
    const float QS = 0.18033688011112042f;
    u16x8 qf[2][2];
    #pragma unroll
    for (int qb = 0; qb < 2; ++qb)
    #pragma unroll
    for (int h = 0; h < 2; ++h) {
        const float* qp = Qg + hoff + (qw0 + 16 * qb + c) * DIM + 32 * h + 8 * g;
        float4 x0 = *(const float4*)qp;
        float4 x1 = *(const float4*)(qp + 4);
        u16x8 u;
        u[0]=f2bf(x0.x*QS); u[1]=f2bf(x0.y*QS); u[2]=f2bf(x0.z*QS); u[3]=f2bf(x0.w*QS);
        u[4]=f2bf(x1.x*QS); u[5]=f2bf(x1.y*QS); u[6]=f2bf(x1.z*QS); u[7]=f2bf(x1.w*QS);
        qf[qb][h] = u;
    }

    f32x4 of[2][4];
    #pragma unroll
    for (int qb = 0; qb < 2; ++qb)
      #pragma unroll
      for (int n = 0; n < 4; ++n) of[qb][n] = (f32x4){0.f, 0.f, 0.f, 0.f};
    float m_run[2] = {-3e38f, -3e38f};
    float l_run[2] = {0.f, 0.f};

    __syncthreads();
    const bool allmask = mflags[0] && mflags[1] && mflags[2] && mflags[3];

    const int ntiles = q0 / 64 + 2;
    for (int t = 0; t < ntiles; ++t) {
        const int kt0 = t * 64;
        __syncthreads();
        // ---- stage K tile [64][64] bf16, row-major, swizzle idx ^= (row&7)<<3 (ushort units)
        {
            const int row = tid >> 2, seg = (tid & 3) << 4;
            const float* kp = Kg + hoff + (kt0 + row) * DIM + seg;
            float4 a0 = ((const float4*)kp)[0];
            float4 a1 = ((const float4*)kp)[1];
            float4 a2 = ((const float4*)kp)[2];
            float4 a3 = ((const float4*)kp)[3];
            u16x8 u0, u1;
            u0[0]=f2bf(a0.x); u0[1]=f2bf(a0.y); u0[2]=f2bf(a0.z); u0[3]=f2bf(a0.w);
            u0[4]=f2bf(a1.x); u0[5]=f2bf(a1.y); u0[6]=f2bf(a1.z); u0[7]=f2bf(a1.w);
            u1[0]=f2bf(a2.x); u1[1]=f2bf(a2.y); u1[2]=f2bf(a2.z); u1[3]=f2bf(a2.w);
            u1[4]=f2bf(a3.x); u1[5]=f2bf(a3.y); u1[6]=f2bf(a3.z); u1[7]=f2bf(a3.w);
            const int sw = (row & 7) << 3;
            *(u16x8*)&Ksh[(row * 64 + seg) ^ sw] = u0;
            *(u16x8*)&Ksh[(row * 64 + seg + 8) ^ sw] = u1;
        }
        // ---- stage V^T [64 d][64 k]: column-gather from global (coalesced across d)
        {
            const int d = tid & 63, kq = (tid >> 6) << 4;
            const float* vp = Vg + hoff + (kt0 + kq) * DIM + d;
            float vv[16];
            #pragma unroll
            for (int i = 0; i < 16; ++i) vv[i] = vp[i * DIM];
            u16x8 u0, u1;
            #pragma unroll
            for (int i = 0; i < 8; ++i) { u0[i] = f2bf(vv[i]); u1[i] = f2bf(vv[i + 8]); }
            const int sw = (d & 7) << 3;
            *(u16x8*)&Vsh[(d * 64 + kq) ^ sw] = u0;
            *(u16x8*)&Vsh[(d * 64 + kq + 8) ^ sw] = u1;
        }
        __syncthreads();

        if (kt0 < qw0 + 32) {   // causal: this wave needs this tile
            unsigned long long bal = allmask ? ~0ULL
                                   : __ballot(Mg[b * SEQ + kt0 + lane] != 0);

            // K A-frags: lane holds K[16m+c][32h+8g+i]
            u16x8 ka[4][2];
            #pragma unroll
            for (int m = 0; m < 4; ++m)
              #pragma unroll
              for (int h = 0; h < 2; ++h)
                ka[m][h] = *(const u16x8*)&Ksh[((m * 16 + c) * 64 + 32 * h + 8 * g) ^ ((c & 7) << 3)];

            // S^T[k][q]: C/D row = k (4g+r within 16-block m), col = q (c)
            f32x4 sv[4][2];
            __builtin_amdgcn_s_setprio(1);
            #pragma unroll
            for (int m = 0; m < 4; ++m)
              #pragma unroll
              for (int qb = 0; qb < 2; ++qb) {
                f32x4 acc = (f32x4){0.f, 0.f, 0.f, 0.f};
                acc = __builtin_amdgcn_mfma_f32_16x16x32_bf16(
                        __builtin_bit_cast(bf16x8, ka[m][0]),
                        __builtin_bit_cast(bf16x8, qf[qb][0]), acc, 0, 0, 0);
                acc = __builtin_amdgcn_mfma_f32_16x16x32_bf16(
                        __builtin_bit_cast(bf16x8, ka[m][1]),
                        __builtin_bit_cast(bf16x8, qf[qb][1]), acc, 0, 0, 0);
                sv[m][qb] = acc;
              }
            __builtin_amdgcn_s_setprio(0);

            // causal mask on the (single) diagonal tile for this wave
            if (kt0 + 63 > qw0) {
                #pragma unroll
                for (int m = 0; m < 4; ++m)
                #pragma unroll
                for (int qb = 0; qb < 2; ++qb) {
                    const int base = kt0 + 16 * m + 4 * g - qw0 - 16 * qb;
                    #pragma unroll
                    for (int r = 0; r < 4; ++r)
                        if (base + r > c) sv[m][qb][r] = -3e38f;
                }
            }
            // padding mask (never taken for all-ones mask)
            if (bal != ~0ULL) {
                #pragma unroll
                for (int m = 0; m < 4; ++m)
                #pragma unroll
                for (int r = 0; r < 4; ++r)
                    if (!((bal >> (16 * m + 4 * g + r)) & 1ULL)) {
                        sv[m][0][r] = -3e38f; sv[m][1][r] = -3e38f;
                    }
            }

            // ---- online softmax per q = 16qb + c (base-2 domain)
            float alpha[2];
            #pragma unroll
            for (int qb = 0; qb < 2; ++qb) {
                float tm = -3e38f;
                #pragma unroll
                for (int m = 0; m < 4; ++m)
                  #pragma unroll
                  for (int r = 0; r < 4; ++r) tm = fmaxf(tm, sv[m][qb][r]);
                tm = fmaxf(tm, __shfl_xor(tm, 16));
                tm = fmaxf(tm, __shfl_xor(tm, 32));
                float mn = fmaxf(m_run[qb], tm);
                alpha[qb] = exp2f(m_run[qb] - mn);
                m_run[qb] = mn;
                float rs = 0.f;
                #pragma unroll
                for (int m = 0; m < 4; ++m)
                  #pragma unroll
                  for (int r = 0; r < 4; ++r) {
                      float p = exp2f(sv[m][qb][r] - mn);
                      sv[m][qb][r] = p;
                      rs += p;
                  }
                rs += __shfl_xor(rs, 16);
                rs += __shfl_xor(rs, 32);
                l_run[qb] = l_run[qb] * alpha[qb] + rs;
            }

            // rescale O accumulators by row-alpha (O rows are 16qb+4g+r)
            #pragma unroll
            for (int qb = 0; qb < 2; ++qb) {
                #pragma unroll
                for (int r = 0; r < 4; ++r) {
                    float ar = __shfl(alpha[qb], 4 * g + r);
                    #pragma unroll
                    for (int n = 0; n < 4; ++n) of[qb][n][r] *= ar;
                }
            }

            // ---- P -> per-wave LDS (bf16), rows q=16qb+c, k contiguous in r
            #pragma unroll
            for (int m = 0; m < 4; ++m)
              #pragma unroll
              for (int qb = 0; qb < 2; ++qb) {
                u16x4 pk;
                #pragma unroll
                for (int r = 0; r < 4; ++r) pk[r] = f2bf(sv[m][qb][r]);
                *(u16x4*)&Psh[w][((16 * qb + c) * 64 + 16 * m + 4 * g) ^ ((c & 7) << 3)] = pk;
              }

            // ---- PV: O[q][d] += P[q][k] V[k][d]
            u16x8 vf[4][2], ap[2][2];
            #pragma unroll
            for (int n = 0; n < 4; ++n)
              #pragma unroll
              for (int h = 0; h < 2; ++h)
                vf[n][h] = *(const u16x8*)&Vsh[((16 * n + c) * 64 + 32 * h + 8 * g) ^ ((c & 7) << 3)];
            #pragma unroll
            for (int qb = 0; qb < 2; ++qb)
              #pragma unroll
              for (int h = 0; h < 2; ++h)
                ap[qb][h] = *(const u16x8*)&Psh[w][((16 * qb + c) * 64 + 32 * h + 8 * g) ^ ((c & 7) << 3)];
            __builtin_amdgcn_s_setprio(1);
            #pragma unroll
            for (int qb = 0; qb < 2; ++qb)
              #pragma unroll
              for (int n = 0; n < 4; ++n) {
                of[qb][n] = __builtin_amdgcn_mfma_f32_16x16x32_bf16(
                    __builtin_bit_cast(bf16x8, ap[qb][0]),
                    __builtin_bit_cast(bf16x8, vf[n][0]), of[qb][n], 0, 0, 0);
                of[qb][n] = __builtin_amdgcn_mfma_f32_16x16x32_bf16(
                    __builtin_bit_cast(bf16x8, ap[qb][1]),
                    __builtin_bit_cast(bf16x8, vf[n][1]), of[qb][n], 0, 0, 0);
              }
            __builtin_amdgcn_s_setprio(0);
        }
    }

    // ---- epilogue: normalize by l and store (f32)
    #pragma unroll
    for (int qb = 0; qb < 2; ++qb) {
        #pragma unroll
        for (int r = 0; r < 4; ++r) {
            float lr = __shfl(l_run[qb], 4 * g + r);
            float inv = 1.0f / lr;
            #pragma unroll
            for (int n = 0; n < 4; ++n)
                Og[hoff + (qw0 + 16 * qb + 4 * g + r) * DIM + 16 * n + c] = of[qb][n][r] * inv;
        }
    }
}

extern "C" void kernel_launch(void* const* d_in, const int* in_sizes, int n_in,
                              void* d_out, int out_size, void* d_ws, size_t ws_size,
                              hipStream_t stream) {
    const float* Q = (const float*)d_in[0];
    const float* K = (const float*)d_in[1];
    const float* V = (const float*)d_in[2];
    const int*   M = (const int*)d_in[3];
    float*       O = (float*)d_out;
    dim3 grid(64, 16);
    attn_fwd<<<grid, 256, 0, stream>>>(Q, K, V, M, O);
}